// Round 8
// baseline (80.014 us; speedup 1.0000x reference)
//
#include <hip/hip_runtime.h>

// PPO loss fused pipeline for MI355X (gfx950).
// R7: fix R5/R6 spill (launch_bounds-induced VGPR=64 + 10-14MB scratch in-loop).
// k_mlp: 1024 blocks x 256 thr (4 waves), 64 rows/block, wave tile 64x64
// (acc[4][4], m97 shape), K-step 32, single-buffer 2-barrier structure,
// __launch_bounds__(256,3) -> VGPR cap 170 (no spill), LDS 52KB -> 3 blocks/CU.

#define TT 65536

typedef float f32x4 __attribute__((ext_vector_type(4)));
typedef __bf16 bf16x8 __attribute__((ext_vector_type(8)));
typedef unsigned short u16x8 __attribute__((ext_vector_type(8)));
typedef unsigned short u16x4 __attribute__((ext_vector_type(4)));

__device__ __forceinline__ unsigned short f2bf(float f) {
    unsigned int u = __float_as_uint(f);
    unsigned int r = (u + 0x7fffu + ((u >> 16) & 1u)) >> 16;
    return (unsigned short)r;
}

// branch-free tanh: 1 - 2/(e^{2x}+1)
__device__ __forceinline__ float fast_tanh(float x) {
    float e = __expf(2.0f * x);
    return fmaf(-2.0f, __builtin_amdgcn_rcpf(e + 1.0f), 1.0f);
}

__device__ __forceinline__ void async_lds16(void* lds, const void* g) {
    __builtin_amdgcn_global_load_lds(
        (const __attribute__((address_space(1))) unsigned int*)g,
        (__attribute__((address_space(3))) unsigned int*)lds, 16, 0, 0);
}

// ---------------- GAE affine suffix scan ----------------
__device__ __forceinline__ void suffix_scan256(float* sC, float* sD, int i) {
    float c = sC[i], d = sD[i];
#pragma unroll
    for (int s = 1; s < 256; s <<= 1) {
        float c2 = 1.0f, d2 = 0.0f;
        if (i + s < 256) { c2 = sC[i + s]; d2 = sD[i + s]; }
        __syncthreads();
        d = d + c * d2;
        c = c * c2;
        sC[i] = c; sD[i] = d;
        __syncthreads();
    }
}

__device__ __forceinline__ void gae_cd(const float* rewards, const float* terms,
                                       const float* values, int t, float* c, float* d) {
    float nt = 1.0f - terms[t];
    float nv = (t + 1 < TT) ? values[t + 1] : 0.0f;
    *d = rewards[t] + 0.99f * nv * nt - values[t];
    *c = 0.99f * 0.95f * nt;
}

// ---------------- fused prep + gae1 ----------------
// Pre-swizzled weight layouts (verified on-device in R6):
//   W1T/W2T: per K-tile kt (8192 elems): chunk L in [0,1024), elem e:
//     row = L>>2, p = L&3, k = kt*32 + ((p ^ ((row>>1)&3))<<3) + e; val = W[k][row]
//   WavT (8192 elems): L: row = L>>5, ec = (L&31)<<3, k = (ec ^ ((row&7)<<3)) + e;
//     rows 0-15 = Wa^T, 16 = Wc^T, 17-31 = 0.
__global__ void k_prep_gae1(const float* __restrict__ W1, const float* __restrict__ W2,
                            const float* __restrict__ Wa, const float* __restrict__ Wc,
                            unsigned short* __restrict__ W1T, unsigned short* __restrict__ W2T,
                            unsigned short* __restrict__ WavT,
                            const float* __restrict__ rewards, const float* __restrict__ terms,
                            const float* __restrict__ values, float* __restrict__ aggC,
                            float* __restrict__ aggD) {
    if (blockIdx.x < 800) {
        int idx = blockIdx.x * 256 + threadIdx.x;
        if (idx < 131072) {
            int kt = idx >> 13;
            int L = (idx & 8191) >> 3, e = idx & 7;
            int row = L >> 2, p = L & 3;
            int k = kt * 32 + (((p ^ ((row >> 1) & 3)) << 3) | e);
            W1T[idx] = f2bf(W1[k * 256 + row]);
        } else if (idx < 196608) {
            int i = idx - 131072;
            int kt = i >> 13;
            int L = (i & 8191) >> 3, e = i & 7;
            int row = L >> 2, p = L & 3;
            int k = kt * 32 + (((p ^ ((row >> 1) & 3)) << 3) | e);
            W2T[i] = f2bf(W2[k * 256 + row]);
        } else if (idx < 204800) {
            int i = idx - 196608;
            int L = i >> 3, e = i & 7;
            int row = L >> 5, ec = (L & 31) << 3;
            int k = ((ec ^ ((row & 7) << 3)) | e);
            float v = (row < 16) ? Wa[k * 16 + row] : ((row == 16) ? Wc[k] : 0.0f);
            WavT[i] = f2bf(v);
        }
        return;
    }
    __shared__ float sC[256], sD[256];
    int i = threadIdx.x;
    int b = blockIdx.x - 800;
    int t = b * 256 + i;
    float c, d;
    gae_cd(rewards, terms, values, t, &c, &d);
    sC[i] = c; sD[i] = d;
    __syncthreads();
    suffix_scan256(sC, sD, i);
    if (i == 0) { aggC[b] = sC[0]; aggD[b] = sD[0]; }
}

// ---------------- gae3: carry + adv/ret + per-block sum partials ----------------
__global__ void k_gae3(const float* __restrict__ rewards, const float* __restrict__ terms,
                       const float* __restrict__ values, const float* __restrict__ aggC,
                       const float* __restrict__ aggD, float* __restrict__ adv,
                       float* __restrict__ ret, float* __restrict__ sumP) {
    __shared__ float sC[256], sD[256];
    int i = threadIdx.x, b = blockIdx.x;
    sC[i] = aggC[i]; sD[i] = aggD[i];
    __syncthreads();
    suffix_scan256(sC, sD, i);
    float carry = (b < 255) ? sD[b + 1] : 0.0f;
    __syncthreads();

    int t = b * 256 + i;
    float c, d;
    gae_cd(rewards, terms, values, t, &c, &d);
    sC[i] = c; sD[i] = d;
    __syncthreads();
    suffix_scan256(sC, sD, i);
    float a = sD[i] + sC[i] * carry;
    adv[t] = a;
    ret[t] = a + values[t];
    __syncthreads();
    sC[i] = a; sD[i] = a * a;
    __syncthreads();
#pragma unroll
    for (int s = 128; s > 0; s >>= 1) {
        if (i < s) { sC[i] += sC[i + s]; sD[i] += sD[i + s]; }
        __syncthreads();
    }
    if (i == 0) { sumP[2 * b] = sC[0]; sumP[2 * b + 1] = sD[0]; }
}

// ---------------- fused MLP + heads + loss (64 rows/block, 4 waves) ----------------
// Wave wid owns output cols [wid*64, +64); acc[4][4] (64 rows x 64 cols).
// LDS 52KB: smB [256][32] 16KB, smA [64][32] 4KB, smH [64][256] 32KB.
// Staged tiles [R][32]: 16B slot' = slot ^ ((row>>1)&3).
// smH swizzle: elem' = elem ^ ((row&7)<<3).
__global__ __launch_bounds__(256, 3) void k_mlp(
    const float* __restrict__ obs, const int* __restrict__ actions,
    const float* __restrict__ logprobs, const float* __restrict__ values,
    const float* __restrict__ b1, const float* __restrict__ b2,
    const float* __restrict__ ba, const float* __restrict__ bc,
    const unsigned short* __restrict__ W1T, const unsigned short* __restrict__ W2T,
    const unsigned short* __restrict__ WavT, const float* __restrict__ adv,
    const float* __restrict__ ret, const float* __restrict__ sumP,
    float* __restrict__ lossP) {
    __shared__ __align__(16) unsigned char SM[53248];
    unsigned short* smB = (unsigned short*)SM;                   // [256][32], 16KB
    unsigned short* smA = (unsigned short*)(SM + 16384);         // [64][32], 4KB
    unsigned short* smH = (unsigned short*)(SM + 20480);         // [64][256], 32KB
    float* red = (float*)(SM + 20480);                           // stats scratch (pre-GEMM)
    float* red2 = (float*)(SM + 16384);                          // loss scratch (post-GEMM)

    const int tid = threadIdx.x;
    const int wid = tid >> 6;
    const int lane = tid & 63;
    const int cl = lane & 15;
    const int gg = lane >> 4;
    const int bm0 = blockIdx.x * 64;

    // A staging map: thread -> 8 floats of one row (one swizzled 8-elem slot)
    const int arow = tid >> 2;                  // 0..63
    const int aslot = tid & 3;                  // 0..3
    const int adst = arow * 32 + ((aslot ^ ((arow >> 1) & 3)) << 3);
    const float* aSrc = obs + (size_t)(bm0 + arow) * 512 + aslot * 8;

    // ---- adv stats (folds gae4); scratch overlays smH (dead until epilogue1) ----
    float meanA, rstdA;
    {
        red[tid] = sumP[2 * tid];
        red[256 + tid] = sumP[2 * tid + 1];
        __syncthreads();
#pragma unroll
        for (int s = 128; s > 0; s >>= 1) {
            if (tid < s) { red[tid] += red[tid + s]; red[256 + tid] += red[256 + tid + s]; }
            __syncthreads();
        }
        meanA = red[0] * (1.0f / TT);
        float var = red[256] * (1.0f / TT) - meanA * meanA;
        rstdA = 1.0f / (sqrtf(fmaxf(var, 0.0f)) + 1e-8f);
        __syncthreads();
    }

    float b1v[4], b2v[4];
#pragma unroll
    for (int n = 0; n < 4; ++n) {
        int c = wid * 64 + n * 16 + cl;
        b1v[n] = b1[c];
        b2v[n] = b2[c];
    }
    const float bav = ba[cl];
    const float bc0 = bc[0];

    f32x4 acc[4][4];
#pragma unroll
    for (int m = 0; m < 4; ++m)
#pragma unroll
        for (int n = 0; n < 4; ++n) acc[m][n] = (f32x4){0.f, 0.f, 0.f, 0.f};

    // ---------------- GEMM1: hidden1 = tanh(obs @ W1 + b1), K=512, 16 tiles ----------------
    for (int t = 0; t < 16; ++t) {
        // stage: B tile t via DMA (pre-swizzled), A tile t via reg-convert
        {
            const unsigned short* bsrc = W1T + t * 8192 + lane * 8;
#pragma unroll
            for (int c = 0; c < 4; ++c) {
                int chunk = wid * 4 + c;
                async_lds16(&smB[chunk * 512], bsrc + chunk * 512);
            }
            float4 a0 = *(const float4*)(aSrc + t * 32);
            float4 a1 = *(const float4*)(aSrc + t * 32 + 4);
            u16x8 cc;
            cc[0] = f2bf(a0.x); cc[1] = f2bf(a0.y); cc[2] = f2bf(a0.z); cc[3] = f2bf(a0.w);
            cc[4] = f2bf(a1.x); cc[5] = f2bf(a1.y); cc[6] = f2bf(a1.z); cc[7] = f2bf(a1.w);
            *(u16x8*)&smA[adst] = cc;
        }
        __syncthreads();   // DMA + ds_writes visible
        bf16x8 av[4], bv[4];
#pragma unroll
        for (int m = 0; m < 4; ++m) {
            int ra = m * 16 + cl;
            av[m] = *(const bf16x8*)&smA[ra * 32 + ((gg ^ ((ra >> 1) & 3)) << 3)];
        }
#pragma unroll
        for (int n = 0; n < 4; ++n) {
            int rb = wid * 64 + n * 16 + cl;
            bv[n] = *(const bf16x8*)&smB[rb * 32 + ((gg ^ ((rb >> 1) & 3)) << 3)];
        }
#pragma unroll
        for (int m = 0; m < 4; ++m)
#pragma unroll
            for (int n = 0; n < 4; ++n)
                acc[m][n] = __builtin_amdgcn_mfma_f32_16x16x32_bf16(av[m], bv[n], acc[m][n], 0, 0, 0);
        __syncthreads();   // compute done; buffers free for next stage
    }

    // epilogue 1: tanh -> smH (swizzled), reset acc
#pragma unroll
    for (int m = 0; m < 4; ++m)
#pragma unroll
        for (int n = 0; n < 4; ++n)
#pragma unroll
            for (int j = 0; j < 4; ++j) {
                int r = m * 16 + gg * 4 + j;
                int c = wid * 64 + n * 16 + cl;
                smH[r * 256 + (c ^ ((r & 7) << 3))] = f2bf(fast_tanh(acc[m][n][j] + b1v[n]));
                acc[m][n][j] = 0.0f;
            }
    __syncthreads();   // hidden1 complete

    // ---------------- GEMM2: hidden = tanh(hidden1 @ W2 + b2), K=256, 8 tiles ----------------
    for (int t = 0; t < 8; ++t) {
        {
            const unsigned short* bsrc = W2T + t * 8192 + lane * 8;
#pragma unroll
            for (int c = 0; c < 4; ++c) {
                int chunk = wid * 4 + c;
                async_lds16(&smB[chunk * 512], bsrc + chunk * 512);
            }
        }
        __syncthreads();
        bf16x8 av[4], bv[4];
#pragma unroll
        for (int m = 0; m < 4; ++m) {
            int ra = m * 16 + cl;
            av[m] = *(const bf16x8*)&smH[ra * 256 + ((t * 32 + gg * 8) ^ ((ra & 7) << 3))];
        }
#pragma unroll
        for (int n = 0; n < 4; ++n) {
            int rb = wid * 64 + n * 16 + cl;
            bv[n] = *(const bf16x8*)&smB[rb * 32 + ((gg ^ ((rb >> 1) & 3)) << 3)];
        }
#pragma unroll
        for (int m = 0; m < 4; ++m)
#pragma unroll
            for (int n = 0; n < 4; ++n)
                acc[m][n] = __builtin_amdgcn_mfma_f32_16x16x32_bf16(av[m], bv[n], acc[m][n], 0, 0, 0);
        __syncthreads();
    }

    // stage head weights (WavT [32][256], smH-style swizzle baked in prep) + epilogue 2
    {
        const unsigned short* bsrc = WavT + lane * 8;
#pragma unroll
        for (int c = 0; c < 4; ++c) {
            int chunk = wid * 4 + c;
            async_lds16(&smB[chunk * 512], bsrc + chunk * 512);
        }
    }
#pragma unroll
    for (int m = 0; m < 4; ++m)
#pragma unroll
        for (int n = 0; n < 4; ++n)
#pragma unroll
            for (int j = 0; j < 4; ++j) {
                int r = m * 16 + gg * 4 + j;
                int c = wid * 64 + n * 16 + cl;
                smH[r * 256 + (c ^ ((r & 7) << 3))] = f2bf(fast_tanh(acc[m][n][j] + b2v[n]));
            }
    __syncthreads();   // hidden + head weights ready

    // ---------------- heads + loss: wave wid owns rows [wid*16, +16) ----------------
    float lsum = 0.0f;
    {
        f32x4 acc_a = {0.f, 0.f, 0.f, 0.f}, acc_v = {0.f, 0.f, 0.f, 0.f};
#pragma unroll
        for (int kk = 0; kk < 8; ++kk) {
            int r = wid * 16 + cl;
            bf16x8 av = *(const bf16x8*)&smH[r * 256 + ((kk * 32 + gg * 8) ^ ((r & 7) << 3))];
            int ra2 = cl;
            bf16x8 bva = *(const bf16x8*)&smB[ra2 * 256 + ((kk * 32 + gg * 8) ^ ((ra2 & 7) << 3))];
            int rv = 16 + cl;
            bf16x8 bvv = *(const bf16x8*)&smB[rv * 256 + ((kk * 32 + gg * 8) ^ ((rv & 7) << 3))];
            acc_a = __builtin_amdgcn_mfma_f32_16x16x32_bf16(av, bva, acc_a, 0, 0, 0);
            acc_v = __builtin_amdgcn_mfma_f32_16x16x32_bf16(av, bvv, acc_v, 0, 0, 0);
        }

        const int t0 = bm0 + wid * 16;
#pragma unroll
        for (int j = 0; j < 4; ++j) {
            int t = t0 + gg * 4 + j;
            float lg = acc_a[j] + bav;
            float mx = lg;
#pragma unroll
            for (int dd = 1; dd < 16; dd <<= 1) mx = fmaxf(mx, __shfl_xor(mx, dd));
            float ex = __expf(lg - mx);
            float se = ex;
#pragma unroll
            for (int dd = 1; dd < 16; dd <<= 1) se += __shfl_xor(se, dd);
            float ls = __logf(se);
            float lp = lg - mx - ls;
            float pl = __expf(lp) * lp;
            float ent = pl;
#pragma unroll
            for (int dd = 1; dd < 16; dd <<= 1) ent += __shfl_xor(ent, dd);
            ent = -ent;
            int act = actions[t];
            float newlp = __shfl(lp, (lane & 48) | act);
            float val = __shfl(acc_v[j], lane & 48) + bc0;

            float lpo = logprobs[t];
            float at = (adv[t] - meanA) * rstdA;
            float rt = ret[t];
            float vo = values[t];
            float ratio = __expf(newlp - lpo);
            float rcl = fminf(fmaxf(ratio, 0.8f), 1.2f);
            float pg = fmaxf(-at * ratio, -at * rcl);
            float vcl = vo + fminf(fmaxf(val - vo, -0.2f), 0.2f);
            float dv = val - rt, dvc = vcl - rt;
            float vl = fmaxf(dv * dv, dvc * dvc);
            if (cl == 0) lsum += pg - 0.01f * ent + 0.25f * vl;
        }
        lsum += __shfl_xor(lsum, 16);
        lsum += __shfl_xor(lsum, 32);
    }
    __syncthreads();   // heads' smB reads done; smA region reusable as red2
    if (lane == 0) red2[wid] = lsum;
    __syncthreads();
    if (tid == 0) lossP[blockIdx.x] = red2[0] + red2[1] + red2[2] + red2[3];
}

__global__ void k_final(const float* __restrict__ lossP, float* __restrict__ out) {
    __shared__ float s[256];
    int i = threadIdx.x;
    s[i] = lossP[i] + lossP[i + 256] + lossP[i + 512] + lossP[i + 768];
    __syncthreads();
#pragma unroll
    for (int st = 128; st > 0; st >>= 1) {
        if (i < st) s[i] += s[i + st];
        __syncthreads();
    }
    if (i == 0) out[0] = s[0] * (1.0f / TT);
}

extern "C" void kernel_launch(void* const* d_in, const int* in_sizes, int n_in,
                              void* d_out, int out_size, void* d_ws, size_t ws_size,
                              hipStream_t stream) {
    const float* obs      = (const float*)d_in[0];
    const int*   actions  = (const int*)d_in[1];
    const float* logprobs = (const float*)d_in[2];
    const float* rewards  = (const float*)d_in[3];
    const float* terms    = (const float*)d_in[4];
    const float* values   = (const float*)d_in[5];
    const float* W1 = (const float*)d_in[6];
    const float* b1 = (const float*)d_in[7];
    const float* W2 = (const float*)d_in[8];
    const float* b2 = (const float*)d_in[9];
    const float* Wa = (const float*)d_in[10];
    const float* ba = (const float*)d_in[11];
    const float* Wc = (const float*)d_in[12];
    const float* bc = (const float*)d_in[13];

    char* ws = (char*)d_ws;
    unsigned short* W1T  = (unsigned short*)(ws + 0);        // 262144 B
    unsigned short* W2T  = (unsigned short*)(ws + 262144);   // 131072 B
    unsigned short* WavT = (unsigned short*)(ws + 393216);   // 16384 B
    float* advp  = (float*)(ws + 409600);                    // 262144 B
    float* retp  = (float*)(ws + 671744);                    // 262144 B
    float* aggC  = (float*)(ws + 933888);                    // 1024 B
    float* aggD  = (float*)(ws + 934912);                    // 1024 B
    float* sumP  = (float*)(ws + 936960);                    // 2048 B
    float* lossP = (float*)(ws + 939072);                    // 4096 B

    k_prep_gae1<<<1056, 256, 0, stream>>>(W1, W2, Wa, Wc, W1T, W2T, WavT,
                                          rewards, terms, values, aggC, aggD);
    k_gae3<<<256, 256, 0, stream>>>(rewards, terms, values, aggC, aggD, advp, retp, sumP);
    k_mlp<<<1024, 256, 0, stream>>>(obs, actions, logprobs, values, b1, b2, ba, bc,
                                    W1T, W2T, WavT, advp, retp, sumP, lossP);
    k_final<<<1, 256, 0, stream>>>(lossP, (float*)d_out);
}

// Round 9
// 75.874 us; speedup vs baseline: 1.0546x; 1.0546x over previous
//
#include <hip/hip_runtime.h>

// PPO loss fused pipeline for MI355X (gfx950).
// R9: T3-min GEMM1 loop (stage t+1 before compute t, ONE barrier/iter),
// LDS 48KB exactly (3 blocks/CU desync; B-dbuf 32K overlaid by smH, A-dbuf+spare
// overlaid by GEMM2-B/Wav), v_cvt_pk_bf16_f32 for all fp32->bf16 (was 4 VALU/elem),
// adv-stats hoisted to 1-block k_gae4 (was redundantly in 1024 blocks).

#define TT 65536

typedef float f32x4 __attribute__((ext_vector_type(4)));
typedef __bf16 bf16x8 __attribute__((ext_vector_type(8)));
typedef unsigned short u16x8 __attribute__((ext_vector_type(8)));
typedef unsigned int u32x4 __attribute__((ext_vector_type(4)));

__device__ __forceinline__ unsigned short f2bf(float f) {
    unsigned int u = __float_as_uint(f);
    unsigned int r = (u + 0x7fffu + ((u >> 16) & 1u)) >> 16;
    return (unsigned short)r;
}

// hw packed fp32->bf16 (RTNE): D[15:0]=bf16(a), D[31:16]=bf16(b)
__device__ __forceinline__ unsigned int cvt_pk_bf16(float a, float b) {
    unsigned int r;
    asm volatile("v_cvt_pk_bf16_f32 %0, %1, %2" : "=v"(r) : "v"(a), "v"(b));
    return r;
}

// branch-free tanh: 1 - 2/(e^{2x}+1)
__device__ __forceinline__ float fast_tanh(float x) {
    float e = __expf(2.0f * x);
    return fmaf(-2.0f, __builtin_amdgcn_rcpf(e + 1.0f), 1.0f);
}

__device__ __forceinline__ void async_lds16(void* lds, const void* g) {
    __builtin_amdgcn_global_load_lds(
        (const __attribute__((address_space(1))) unsigned int*)g,
        (__attribute__((address_space(3))) unsigned int*)lds, 16, 0, 0);
}

// ---------------- GAE affine suffix scan ----------------
__device__ __forceinline__ void suffix_scan256(float* sC, float* sD, int i) {
    float c = sC[i], d = sD[i];
#pragma unroll
    for (int s = 1; s < 256; s <<= 1) {
        float c2 = 1.0f, d2 = 0.0f;
        if (i + s < 256) { c2 = sC[i + s]; d2 = sD[i + s]; }
        __syncthreads();
        d = d + c * d2;
        c = c * c2;
        sC[i] = c; sD[i] = d;
        __syncthreads();
    }
}

__device__ __forceinline__ void gae_cd(const float* rewards, const float* terms,
                                       const float* values, int t, float* c, float* d) {
    float nt = 1.0f - terms[t];
    float nv = (t + 1 < TT) ? values[t + 1] : 0.0f;
    *d = rewards[t] + 0.99f * nv * nt - values[t];
    *c = 0.99f * 0.95f * nt;
}

// ---------------- fused prep + gae1 ----------------
// Pre-swizzled weight layouts (verified on-device R6/R7):
//   W1T/W2T: per K-tile kt (8192 elems): chunk L in [0,1024), elem e:
//     row = L>>2, p = L&3, k = kt*32 + ((p ^ ((row>>1)&3))<<3) + e; val = W[k][row]
//   WavT (8192 elems): L: row = L>>5, ec = (L&31)<<3, k = (ec ^ ((row&7)<<3)) + e;
//     rows 0-15 = Wa^T, 16 = Wc^T, 17-31 = 0.
__global__ void k_prep_gae1(const float* __restrict__ W1, const float* __restrict__ W2,
                            const float* __restrict__ Wa, const float* __restrict__ Wc,
                            unsigned short* __restrict__ W1T, unsigned short* __restrict__ W2T,
                            unsigned short* __restrict__ WavT,
                            const float* __restrict__ rewards, const float* __restrict__ terms,
                            const float* __restrict__ values, float* __restrict__ aggC,
                            float* __restrict__ aggD) {
    if (blockIdx.x < 800) {
        int idx = blockIdx.x * 256 + threadIdx.x;
        if (idx < 131072) {
            int kt = idx >> 13;
            int L = (idx & 8191) >> 3, e = idx & 7;
            int row = L >> 2, p = L & 3;
            int k = kt * 32 + (((p ^ ((row >> 1) & 3)) << 3) | e);
            W1T[idx] = f2bf(W1[k * 256 + row]);
        } else if (idx < 196608) {
            int i = idx - 131072;
            int kt = i >> 13;
            int L = (i & 8191) >> 3, e = i & 7;
            int row = L >> 2, p = L & 3;
            int k = kt * 32 + (((p ^ ((row >> 1) & 3)) << 3) | e);
            W2T[i] = f2bf(W2[k * 256 + row]);
        } else if (idx < 204800) {
            int i = idx - 196608;
            int L = i >> 3, e = i & 7;
            int row = L >> 5, ec = (L & 31) << 3;
            int k = ((ec ^ ((row & 7) << 3)) | e);
            float v = (row < 16) ? Wa[k * 16 + row] : ((row == 16) ? Wc[k] : 0.0f);
            WavT[i] = f2bf(v);
        }
        return;
    }
    __shared__ float sC[256], sD[256];
    int i = threadIdx.x;
    int b = blockIdx.x - 800;
    int t = b * 256 + i;
    float c, d;
    gae_cd(rewards, terms, values, t, &c, &d);
    sC[i] = c; sD[i] = d;
    __syncthreads();
    suffix_scan256(sC, sD, i);
    if (i == 0) { aggC[b] = sC[0]; aggD[b] = sD[0]; }
}

// ---------------- gae3: carry + adv/ret + per-block sum partials ----------------
__global__ void k_gae3(const float* __restrict__ rewards, const float* __restrict__ terms,
                       const float* __restrict__ values, const float* __restrict__ aggC,
                       const float* __restrict__ aggD, float* __restrict__ adv,
                       float* __restrict__ ret, float* __restrict__ sumP) {
    __shared__ float sC[256], sD[256];
    int i = threadIdx.x, b = blockIdx.x;
    sC[i] = aggC[i]; sD[i] = aggD[i];
    __syncthreads();
    suffix_scan256(sC, sD, i);
    float carry = (b < 255) ? sD[b + 1] : 0.0f;
    __syncthreads();

    int t = b * 256 + i;
    float c, d;
    gae_cd(rewards, terms, values, t, &c, &d);
    sC[i] = c; sD[i] = d;
    __syncthreads();
    suffix_scan256(sC, sD, i);
    float a = sD[i] + sC[i] * carry;
    adv[t] = a;
    ret[t] = a + values[t];
    __syncthreads();
    sC[i] = a; sD[i] = a * a;
    __syncthreads();
#pragma unroll
    for (int s = 128; s > 0; s >>= 1) {
        if (i < s) { sC[i] += sC[i + s]; sD[i] += sD[i + s]; }
        __syncthreads();
    }
    if (i == 0) { sumP[2 * b] = sC[0]; sumP[2 * b + 1] = sD[0]; }
}

// ---------------- gae4: adv mean / rstd (1 block) ----------------
__global__ void k_gae4(const float* __restrict__ sumP, float* __restrict__ stats) {
    __shared__ float s1[256], s2[256];
    int i = threadIdx.x;
    s1[i] = sumP[2 * i]; s2[i] = sumP[2 * i + 1];
    __syncthreads();
#pragma unroll
    for (int s = 128; s > 0; s >>= 1) {
        if (i < s) { s1[i] += s1[i + s]; s2[i] += s2[i + s]; }
        __syncthreads();
    }
    if (i == 0) {
        float mean = s1[0] * (1.0f / TT);
        float var = s2[0] * (1.0f / TT) - mean * mean;
        stats[0] = mean;
        stats[1] = 1.0f / (sqrtf(fmaxf(var, 0.0f)) + 1e-8f);
    }
}

// ---------------- fused MLP + heads + loss (64 rows/block, 4 waves) ----------------
// Wave wid owns output cols [wid*64, +64); acc[4][4].
// LDS 48KB: [0,32K) B1 dbuf (2x16K) -> smH [64][256] after GEMM1;
//           [32K,40K) A dbuf (2x4K); [32K,48K) GEMM2-B / Wav (after GEMM1).
// Staged tiles [R][32]: 16B slot' = slot ^ ((row>>1)&3).
// smH swizzle: elem' = elem ^ ((row&7)<<3).
__global__ __launch_bounds__(256, 3) void k_mlp(
    const float* __restrict__ obs, const int* __restrict__ actions,
    const float* __restrict__ logprobs, const float* __restrict__ values,
    const float* __restrict__ b1, const float* __restrict__ b2,
    const float* __restrict__ ba, const float* __restrict__ bc,
    const unsigned short* __restrict__ W1T, const unsigned short* __restrict__ W2T,
    const unsigned short* __restrict__ WavT, const float* __restrict__ adv,
    const float* __restrict__ ret, const float* __restrict__ stats,
    float* __restrict__ lossP) {
    __shared__ __align__(16) unsigned char SM[49152];
    unsigned short* smB1 = (unsigned short*)SM;                  // 2 x 8192 elems (GEMM1)
    unsigned short* smA  = (unsigned short*)(SM + 32768);        // 2 x 2048 elems
    unsigned short* smH  = (unsigned short*)SM;                  // [64][256] after GEMM1
    unsigned short* smB2 = (unsigned short*)(SM + 32768);        // [256][32] / Wav [32][256]

    const int tid = threadIdx.x;
    const int wid = tid >> 6;
    const int lane = tid & 63;
    const int cl = lane & 15;
    const int gg = lane >> 4;
    const int bm0 = blockIdx.x * 64;

    // A staging map: thread -> 8 floats of one row (one swizzled 8-elem slot)
    const int arow = tid >> 2;                  // 0..63
    const int aslot = tid & 3;                  // 0..3
    const int adst = arow * 32 + ((aslot ^ ((arow >> 1) & 3)) << 3);
    const float* aSrc = obs + (size_t)(bm0 + arow) * 512 + aslot * 8;

    const float meanA = stats[0], rstdA = stats[1];

    float b1v[4], b2v[4];
#pragma unroll
    for (int n = 0; n < 4; ++n) {
        int c = wid * 64 + n * 16 + cl;
        b1v[n] = b1[c];
        b2v[n] = b2[c];
    }
    const float bav = ba[cl];
    const float bc0 = bc[0];

    f32x4 acc[4][4];
#pragma unroll
    for (int m = 0; m < 4; ++m)
#pragma unroll
        for (int n = 0; n < 4; ++n) acc[m][n] = (f32x4){0.f, 0.f, 0.f, 0.f};

    // stage a 8192-elem pre-swizzled tile into a 16KB LDS region (4 chunks/wave)
    auto stageTile = [&](const unsigned short* src, unsigned short* dst) {
#pragma unroll
        for (int c = 0; c < 4; ++c) {
            int chunk = wid * 4 + c;
            async_lds16(dst + chunk * 512, src + chunk * 512 + lane * 8);
        }
    };
    auto cvtWriteA = [&](const float4& f0, const float4& f1, int buf) {
        u32x4 pk;
        pk[0] = cvt_pk_bf16(f0.x, f0.y);
        pk[1] = cvt_pk_bf16(f0.z, f0.w);
        pk[2] = cvt_pk_bf16(f1.x, f1.y);
        pk[3] = cvt_pk_bf16(f1.z, f1.w);
        *(u32x4*)&smA[buf * 2048 + adst] = pk;
    };

    // ---------------- GEMM1: hidden1 = tanh(obs @ W1 + b1), K=512, 16 tiles ----------------
    // T3-min: stage(t+1) issued before compute(t); ONE barrier per iter.
    {
        float4 a0 = *(const float4*)(aSrc);
        float4 a1 = *(const float4*)(aSrc + 4);
        stageTile(W1T, smB1);
        cvtWriteA(a0, a1, 0);
        __syncthreads();
#pragma unroll
        for (int t = 0; t < 16; ++t) {
            if (t < 15) {
                a0 = *(const float4*)(aSrc + (t + 1) * 32);
                a1 = *(const float4*)(aSrc + (t + 1) * 32 + 4);
                stageTile(W1T + (t + 1) * 8192, smB1 + ((t + 1) & 1) * 8192);
            }
            bf16x8 av[4], bv[4];
#pragma unroll
            for (int m = 0; m < 4; ++m) {
                int ra = m * 16 + cl;
                av[m] = *(const bf16x8*)&smA[(t & 1) * 2048 + ra * 32 + ((gg ^ ((ra >> 1) & 3)) << 3)];
            }
#pragma unroll
            for (int n = 0; n < 4; ++n) {
                int rb = wid * 64 + n * 16 + cl;
                bv[n] = *(const bf16x8*)&smB1[(t & 1) * 8192 + rb * 32 + ((gg ^ ((rb >> 1) & 3)) << 3)];
            }
#pragma unroll
            for (int m = 0; m < 4; ++m)
#pragma unroll
                for (int n = 0; n < 4; ++n)
                    acc[m][n] = __builtin_amdgcn_mfma_f32_16x16x32_bf16(av[m], bv[n], acc[m][n], 0, 0, 0);
            if (t < 15) cvtWriteA(a0, a1, (t + 1) & 1);   // loads had compute phase to land
            __syncthreads();
        }
    }

    // epilogue 1: issue GEMM2 tile-0 DMA (A-dbuf region now dead), tanh -> smH
    stageTile(W2T, smB2);
#pragma unroll
    for (int m = 0; m < 4; ++m)
#pragma unroll
        for (int n = 0; n < 4; ++n)
#pragma unroll
            for (int jp = 0; jp < 2; ++jp) {
                float v0 = fast_tanh(acc[m][n][2 * jp] + b1v[n]);
                float v1 = fast_tanh(acc[m][n][2 * jp + 1] + b1v[n]);
                unsigned int p = cvt_pk_bf16(v0, v1);
                int r0 = m * 16 + gg * 4 + 2 * jp;
                int c = wid * 64 + n * 16 + cl;
                smH[r0 * 256 + (c ^ ((r0 & 7) << 3))] = (unsigned short)p;
                int r1 = r0 + 1;
                smH[r1 * 256 + (c ^ ((r1 & 7) << 3))] = (unsigned short)(p >> 16);
                acc[m][n][2 * jp] = 0.0f;
                acc[m][n][2 * jp + 1] = 0.0f;
            }
    __syncthreads();   // smH visible + GEMM2 tile-0 DMA drained

    // ---------------- GEMM2: hidden = tanh(hidden1 @ W2 + b2), K=256, 8 tiles ----------------
#pragma unroll
    for (int t = 0; t < 8; ++t) {
        bf16x8 av[4], bv[4];
#pragma unroll
        for (int m = 0; m < 4; ++m) {
            int ra = m * 16 + cl;
            av[m] = *(const bf16x8*)&smH[ra * 256 + ((t * 32 + gg * 8) ^ ((ra & 7) << 3))];
        }
#pragma unroll
        for (int n = 0; n < 4; ++n) {
            int rb = wid * 64 + n * 16 + cl;
            bv[n] = *(const bf16x8*)&smB2[rb * 32 + ((gg ^ ((rb >> 1) & 3)) << 3)];
        }
#pragma unroll
        for (int m = 0; m < 4; ++m)
#pragma unroll
            for (int n = 0; n < 4; ++n)
                acc[m][n] = __builtin_amdgcn_mfma_f32_16x16x32_bf16(av[m], bv[n], acc[m][n], 0, 0, 0);
        __syncthreads();   // smB2 reads done
        if (t < 7) stageTile(W2T + (t + 1) * 8192, smB2);
        else       stageTile(WavT, smB2);
        __syncthreads();   // DMA drained
    }

    // epilogue 2: hidden -> smH (Wav already staged into smB2)
#pragma unroll
    for (int m = 0; m < 4; ++m)
#pragma unroll
        for (int n = 0; n < 4; ++n)
#pragma unroll
            for (int jp = 0; jp < 2; ++jp) {
                float v0 = fast_tanh(acc[m][n][2 * jp] + b2v[n]);
                float v1 = fast_tanh(acc[m][n][2 * jp + 1] + b2v[n]);
                unsigned int p = cvt_pk_bf16(v0, v1);
                int r0 = m * 16 + gg * 4 + 2 * jp;
                int c = wid * 64 + n * 16 + cl;
                smH[r0 * 256 + (c ^ ((r0 & 7) << 3))] = (unsigned short)p;
                int r1 = r0 + 1;
                smH[r1 * 256 + (c ^ ((r1 & 7) << 3))] = (unsigned short)(p >> 16);
            }
    __syncthreads();   // hidden + head weights ready

    // ---------------- heads + loss: wave wid owns rows [wid*16, +16) ----------------
    float lsum = 0.0f;
    {
        f32x4 acc_a = {0.f, 0.f, 0.f, 0.f}, acc_v = {0.f, 0.f, 0.f, 0.f};
#pragma unroll
        for (int kk = 0; kk < 8; ++kk) {
            int r = wid * 16 + cl;
            bf16x8 av = *(const bf16x8*)&smH[r * 256 + ((kk * 32 + gg * 8) ^ ((r & 7) << 3))];
            int ra2 = cl;
            bf16x8 bva = *(const bf16x8*)&smB2[ra2 * 256 + ((kk * 32 + gg * 8) ^ ((ra2 & 7) << 3))];
            int rv = 16 + cl;
            bf16x8 bvv = *(const bf16x8*)&smB2[rv * 256 + ((kk * 32 + gg * 8) ^ ((rv & 7) << 3))];
            acc_a = __builtin_amdgcn_mfma_f32_16x16x32_bf16(av, bva, acc_a, 0, 0, 0);
            acc_v = __builtin_amdgcn_mfma_f32_16x16x32_bf16(av, bvv, acc_v, 0, 0, 0);
        }

        const int t0 = bm0 + wid * 16;
#pragma unroll
        for (int j = 0; j < 4; ++j) {
            int t = t0 + gg * 4 + j;
            float lg = acc_a[j] + bav;
            float mx = lg;
#pragma unroll
            for (int dd = 1; dd < 16; dd <<= 1) mx = fmaxf(mx, __shfl_xor(mx, dd));
            float ex = __expf(lg - mx);
            float se = ex;
#pragma unroll
            for (int dd = 1; dd < 16; dd <<= 1) se += __shfl_xor(se, dd);
            float ls = __logf(se);
            float lp = lg - mx - ls;
            float pl = __expf(lp) * lp;
            float ent = pl;
#pragma unroll
            for (int dd = 1; dd < 16; dd <<= 1) ent += __shfl_xor(ent, dd);
            ent = -ent;
            int act = actions[t];
            float newlp = __shfl(lp, (lane & 48) | act);
            float val = __shfl(acc_v[j], lane & 48) + bc0;

            float lpo = logprobs[t];
            float at = (adv[t] - meanA) * rstdA;
            float rt = ret[t];
            float vo = values[t];
            float ratio = __expf(newlp - lpo);
            float rcl = fminf(fmaxf(ratio, 0.8f), 1.2f);
            float pg = fmaxf(-at * ratio, -at * rcl);
            float vcl = vo + fminf(fmaxf(val - vo, -0.2f), 0.2f);
            float dv = val - rt, dvc = vcl - rt;
            float vl = fmaxf(dv * dv, dvc * dvc);
            if (cl == 0) lsum += pg - 0.01f * ent + 0.25f * vl;
        }
        lsum += __shfl_xor(lsum, 16);
        lsum += __shfl_xor(lsum, 32);
    }
    __syncthreads();   // all LDS reads done; reuse SM[0..] for final reduce
    float* red2 = (float*)SM;
    if (lane == 0) red2[wid] = lsum;
    __syncthreads();
    if (tid == 0) lossP[blockIdx.x] = red2[0] + red2[1] + red2[2] + red2[3];
}

__global__ void k_final(const float* __restrict__ lossP, float* __restrict__ out) {
    __shared__ float s[256];
    int i = threadIdx.x;
    s[i] = lossP[i] + lossP[i + 256] + lossP[i + 512] + lossP[i + 768];
    __syncthreads();
#pragma unroll
    for (int st = 128; st > 0; st >>= 1) {
        if (i < st) s[i] += s[i + st];
        __syncthreads();
    }
    if (i == 0) out[0] = s[0] * (1.0f / TT);
}

extern "C" void kernel_launch(void* const* d_in, const int* in_sizes, int n_in,
                              void* d_out, int out_size, void* d_ws, size_t ws_size,
                              hipStream_t stream) {
    const float* obs      = (const float*)d_in[0];
    const int*   actions  = (const int*)d_in[1];
    const float* logprobs = (const float*)d_in[2];
    const float* rewards  = (const float*)d_in[3];
    const float* terms    = (const float*)d_in[4];
    const float* values   = (const float*)d_in[5];
    const float* W1 = (const float*)d_in[6];
    const float* b1 = (const float*)d_in[7];
    const float* W2 = (const float*)d_in[8];
    const float* b2 = (const float*)d_in[9];
    const float* Wa = (const float*)d_in[10];
    const float* ba = (const float*)d_in[11];
    const float* Wc = (const float*)d_in[12];
    const float* bc = (const float*)d_in[13];

    char* ws = (char*)d_ws;
    unsigned short* W1T  = (unsigned short*)(ws + 0);        // 262144 B
    unsigned short* W2T  = (unsigned short*)(ws + 262144);   // 131072 B
    unsigned short* WavT = (unsigned short*)(ws + 393216);   // 16384 B
    float* advp  = (float*)(ws + 409600);                    // 262144 B
    float* retp  = (float*)(ws + 671744);                    // 262144 B
    float* aggC  = (float*)(ws + 933888);                    // 1024 B
    float* aggD  = (float*)(ws + 934912);                    // 1024 B
    float* sumP  = (float*)(ws + 936960);                    // 2048 B
    float* stats = (float*)(ws + 939008);                    // 64 B
    float* lossP = (float*)(ws + 939072);                    // 4096 B

    k_prep_gae1<<<1056, 256, 0, stream>>>(W1, W2, Wa, Wc, W1T, W2T, WavT,
                                          rewards, terms, values, aggC, aggD);
    k_gae3<<<256, 256, 0, stream>>>(rewards, terms, values, aggC, aggD, advp, retp, sumP);
    k_gae4<<<1, 256, 0, stream>>>(sumP, stats);
    k_mlp<<<1024, 256, 0, stream>>>(obs, actions, logprobs, values, b1, b2, ba, bc,
                                    W1T, W2T, WavT, advp, retp, stats, lossP);
    k_final<<<1, 256, 0, stream>>>(lossP, (float*)d_out);
}

// Round 10
// 66.537 us; speedup vs baseline: 1.2025x; 1.1403x over previous
//
#include <hip/hip_runtime.h>

// PPO loss fused pipeline for MI355X (gfx950).
// R10: B-matrices NEVER touch LDS. k_prep emits weights in MFMA-fragment-major
// layout (frag[kt][nt][lane][8] = lane-contiguous 1KB blocks); bv = one coalesced
// 16B/lane global load from L2-warm memory. LDS = A dbuf 8KB + smH 32KB = 40KB
// -> 4 blocks/CU. GEMM2 + heads: ZERO barriers in loop (smH read-only, B global).
// GEMM1: 1 barrier/iter (A dbuf only). Fixes the 9-round 24%-occupancy trap.

#define TT 65536

typedef float f32x4 __attribute__((ext_vector_type(4)));
typedef __bf16 bf16x8 __attribute__((ext_vector_type(8)));
typedef unsigned short u16x8 __attribute__((ext_vector_type(8)));
typedef unsigned int u32x4 __attribute__((ext_vector_type(4)));

__device__ __forceinline__ unsigned short f2bf(float f) {
    unsigned int u = __float_as_uint(f);
    unsigned int r = (u + 0x7fffu + ((u >> 16) & 1u)) >> 16;
    return (unsigned short)r;
}

// hw packed fp32->bf16 (RTNE), non-volatile so the scheduler may move/CSE it
__device__ __forceinline__ unsigned int cvt_pk_bf16(float a, float b) {
    unsigned int r;
    asm("v_cvt_pk_bf16_f32 %0, %1, %2" : "=v"(r) : "v"(a), "v"(b));
    return r;
}

// branch-free tanh: 1 - 2/(e^{2x}+1)
__device__ __forceinline__ float fast_tanh(float x) {
    float e = __expf(2.0f * x);
    return fmaf(-2.0f, __builtin_amdgcn_rcpf(e + 1.0f), 1.0f);
}

// ---------------- GAE affine suffix scan ----------------
__device__ __forceinline__ void suffix_scan256(float* sC, float* sD, int i) {
    float c = sC[i], d = sD[i];
#pragma unroll
    for (int s = 1; s < 256; s <<= 1) {
        float c2 = 1.0f, d2 = 0.0f;
        if (i + s < 256) { c2 = sC[i + s]; d2 = sD[i + s]; }
        __syncthreads();
        d = d + c * d2;
        c = c * c2;
        sC[i] = c; sD[i] = d;
        __syncthreads();
    }
}

__device__ __forceinline__ void gae_cd(const float* rewards, const float* terms,
                                       const float* values, int t, float* c, float* d) {
    float nt = 1.0f - terms[t];
    float nv = (t + 1 < TT) ? values[t + 1] : 0.0f;
    *d = rewards[t] + 0.99f * nv * nt - values[t];
    *c = 0.99f * 0.95f * nt;
}

// ---------------- fused prep + gae1 ----------------
// Fragment-major weight layouts (B-frag of mfma_f32_16x16x32_bf16:
//   lane l holds W[k = kt*32 + (l>>4)*8 + e][col = base + (l&15)], e=0..7):
//   W1Tf[kt 0..15][nt 0..15][l 0..63][e 0..7]  (131072 elems)
//   W2Tf[kt 0..7 ][nt 0..15][l 0..63][e 0..7]  ( 65536 elems)
//   Wavf[kt 0..7 ][h 0..1  ][l 0..63][e 0..7]  (  8192 elems)
//     h=0: Wa cols 0-15; h=1: col0 = Wc, cols 1-15 = 0.
__global__ void k_prep_gae1(const float* __restrict__ W1, const float* __restrict__ W2,
                            const float* __restrict__ Wa, const float* __restrict__ Wc,
                            unsigned short* __restrict__ W1Tf, unsigned short* __restrict__ W2Tf,
                            unsigned short* __restrict__ Wavf,
                            const float* __restrict__ rewards, const float* __restrict__ terms,
                            const float* __restrict__ values, float* __restrict__ aggC,
                            float* __restrict__ aggD) {
    if (blockIdx.x < 800) {
        int idx = blockIdx.x * 256 + threadIdx.x;
        if (idx < 131072) {
            int e = idx & 7, l = (idx >> 3) & 63, nt = (idx >> 9) & 15, kt = idx >> 13;
            int col = nt * 16 + (l & 15);
            int k = kt * 32 + ((l >> 4) << 3) + e;
            W1Tf[idx] = f2bf(W1[k * 256 + col]);
        } else if (idx < 196608) {
            int i = idx - 131072;
            int e = i & 7, l = (i >> 3) & 63, nt = (i >> 9) & 15, kt = i >> 13;
            int col = nt * 16 + (l & 15);
            int k = kt * 32 + ((l >> 4) << 3) + e;
            W2Tf[i] = f2bf(W2[k * 256 + col]);
        } else if (idx < 204800) {
            int i = idx - 196608;
            int e = i & 7, l = (i >> 3) & 63, h = (i >> 9) & 1, kt = i >> 10;
            int k = kt * 32 + ((l >> 4) << 3) + e;
            int a = l & 15;
            float v = (h == 0) ? Wa[k * 16 + a] : ((a == 0) ? Wc[k] : 0.0f);
            Wavf[i] = f2bf(v);
        }
        return;
    }
    __shared__ float sC[256], sD[256];
    int i = threadIdx.x;
    int b = blockIdx.x - 800;
    int t = b * 256 + i;
    float c, d;
    gae_cd(rewards, terms, values, t, &c, &d);
    sC[i] = c; sD[i] = d;
    __syncthreads();
    suffix_scan256(sC, sD, i);
    if (i == 0) { aggC[b] = sC[0]; aggD[b] = sD[0]; }
}

// ---------------- gae3: carry + adv/ret + per-block sum partials ----------------
__global__ void k_gae3(const float* __restrict__ rewards, const float* __restrict__ terms,
                       const float* __restrict__ values, const float* __restrict__ aggC,
                       const float* __restrict__ aggD, float* __restrict__ adv,
                       float* __restrict__ ret, float* __restrict__ sumP) {
    __shared__ float sC[256], sD[256];
    int i = threadIdx.x, b = blockIdx.x;
    sC[i] = aggC[i]; sD[i] = aggD[i];
    __syncthreads();
    suffix_scan256(sC, sD, i);
    float carry = (b < 255) ? sD[b + 1] : 0.0f;
    __syncthreads();

    int t = b * 256 + i;
    float c, d;
    gae_cd(rewards, terms, values, t, &c, &d);
    sC[i] = c; sD[i] = d;
    __syncthreads();
    suffix_scan256(sC, sD, i);
    float a = sD[i] + sC[i] * carry;
    adv[t] = a;
    ret[t] = a + values[t];
    __syncthreads();
    sC[i] = a; sD[i] = a * a;
    __syncthreads();
#pragma unroll
    for (int s = 128; s > 0; s >>= 1) {
        if (i < s) { sC[i] += sC[i + s]; sD[i] += sD[i + s]; }
        __syncthreads();
    }
    if (i == 0) { sumP[2 * b] = sC[0]; sumP[2 * b + 1] = sD[0]; }
}

// ---------------- gae4: adv mean / rstd (1 block) ----------------
__global__ void k_gae4(const float* __restrict__ sumP, float* __restrict__ stats) {
    __shared__ float s1[256], s2[256];
    int i = threadIdx.x;
    s1[i] = sumP[2 * i]; s2[i] = sumP[2 * i + 1];
    __syncthreads();
#pragma unroll
    for (int s = 128; s > 0; s >>= 1) {
        if (i < s) { s1[i] += s1[i + s]; s2[i] += s2[i + s]; }
        __syncthreads();
    }
    if (i == 0) {
        float mean = s1[0] * (1.0f / TT);
        float var = s2[0] * (1.0f / TT) - mean * mean;
        stats[0] = mean;
        stats[1] = 1.0f / (sqrtf(fmaxf(var, 0.0f)) + 1e-8f);
    }
}

// ---------------- fused MLP + heads + loss (64 rows/block, 4 waves) ----------------
// Wave wid owns output cols [wid*64, +64); acc[4][4].
// LDS 40KB: [0,8K) A dbuf (2 x [64][32] bf16); [8K,40K) smH [64][256].
// A tiles swizzle: 16B slot' = slot ^ ((row>>1)&3).  smH: elem' = elem ^ ((row&7)<<3).
// B fragments: direct global loads from fragment-major W1Tf/W2Tf/Wavf (L2-warm).
__global__ __launch_bounds__(256, 3) void k_mlp(
    const float* __restrict__ obs, const int* __restrict__ actions,
    const float* __restrict__ logprobs, const float* __restrict__ values,
    const float* __restrict__ b1, const float* __restrict__ b2,
    const float* __restrict__ ba, const float* __restrict__ bc,
    const unsigned short* __restrict__ W1Tf, const unsigned short* __restrict__ W2Tf,
    const unsigned short* __restrict__ Wavf, const float* __restrict__ adv,
    const float* __restrict__ ret, const float* __restrict__ stats,
    float* __restrict__ lossP) {
    __shared__ __align__(16) unsigned char SM[40960];
    unsigned short* smA = (unsigned short*)SM;                   // 2 x 2048 elems
    unsigned short* smH = (unsigned short*)(SM + 8192);          // [64][256]

    const int tid = threadIdx.x;
    const int wid = tid >> 6;
    const int lane = tid & 63;
    const int cl = lane & 15;
    const int gg = lane >> 4;
    const int bm0 = blockIdx.x * 64;

    // A staging map: thread -> 8 floats of one row (one swizzled 8-elem slot)
    const int arow = tid >> 2;                  // 0..63
    const int aslot = tid & 3;                  // 0..3
    const int adst = arow * 32 + ((aslot ^ ((arow >> 1) & 3)) << 3);
    const float* aSrc = obs + (size_t)(bm0 + arow) * 512 + aslot * 8;

    const float meanA = stats[0], rstdA = stats[1];

    float b1v[4], b2v[4];
#pragma unroll
    for (int n = 0; n < 4; ++n) {
        int c = wid * 64 + n * 16 + cl;
        b1v[n] = b1[c];
        b2v[n] = b2[c];
    }
    const float bav = ba[cl];
    const float bc0 = bc[0];

    f32x4 acc[4][4];
#pragma unroll
    for (int m = 0; m < 4; ++m)
#pragma unroll
        for (int n = 0; n < 4; ++n) acc[m][n] = (f32x4){0.f, 0.f, 0.f, 0.f};

    auto cvtWriteA = [&](const float4& f0, const float4& f1, int buf) {
        u32x4 pk;
        pk[0] = cvt_pk_bf16(f0.x, f0.y);
        pk[1] = cvt_pk_bf16(f0.z, f0.w);
        pk[2] = cvt_pk_bf16(f1.x, f1.y);
        pk[3] = cvt_pk_bf16(f1.z, f1.w);
        *(u32x4*)&smA[buf * 2048 + adst] = pk;
    };

    // ---------------- GEMM1: hidden1 = tanh(obs @ W1 + b1), K=512, 16 tiles ----------------
    // B frags direct from global; only A goes through LDS (dbuf, 1 barrier/iter).
    {
        // per-wave fragment base: frag (kt, nt=wid*4+n) at ((kt*16+nt)*64 + lane)*8
        const unsigned short* bBase = W1Tf + ((size_t)(wid * 4) << 9) + lane * 8;
        float4 a0 = *(const float4*)(aSrc);
        float4 a1 = *(const float4*)(aSrc + 4);
        cvtWriteA(a0, a1, 0);
        __syncthreads();
#pragma unroll
        for (int t = 0; t < 16; ++t) {
            if (t < 15) {
                a0 = *(const float4*)(aSrc + (t + 1) * 32);
                a1 = *(const float4*)(aSrc + (t + 1) * 32 + 4);
            }
            bf16x8 av[4], bv[4];
#pragma unroll
            for (int n = 0; n < 4; ++n)
                bv[n] = *(const bf16x8*)(bBase + ((size_t)(t * 16 + n) << 9));
#pragma unroll
            for (int m = 0; m < 4; ++m) {
                int ra = m * 16 + cl;
                av[m] = *(const bf16x8*)&smA[(t & 1) * 2048 + ra * 32 + ((gg ^ ((ra >> 1) & 3)) << 3)];
            }
#pragma unroll
            for (int m = 0; m < 4; ++m)
#pragma unroll
                for (int n = 0; n < 4; ++n)
                    acc[m][n] = __builtin_amdgcn_mfma_f32_16x16x32_bf16(av[m], bv[n], acc[m][n], 0, 0, 0);
            if (t < 15) cvtWriteA(a0, a1, (t + 1) & 1);
            __syncthreads();
        }
    }

    // epilogue 1: tanh -> smH (swizzled), reset acc
#pragma unroll
    for (int m = 0; m < 4; ++m)
#pragma unroll
        for (int n = 0; n < 4; ++n)
#pragma unroll
            for (int j = 0; j < 4; ++j) {
                int r = m * 16 + gg * 4 + j;
                int c = wid * 64 + n * 16 + cl;
                smH[r * 256 + (c ^ ((r & 7) << 3))] = f2bf(fast_tanh(acc[m][n][j] + b1v[n]));
                acc[m][n][j] = 0.0f;
            }
    __syncthreads();   // hidden1 visible; smH read-only from here to epilogue2

    // ---------------- GEMM2: hidden = tanh(hidden1 @ W2 + b2), K=256 — NO barriers ----------------
    {
        const unsigned short* bBase = W2Tf + ((size_t)(wid * 4) << 9) + lane * 8;
#pragma unroll
        for (int t = 0; t < 8; ++t) {
            bf16x8 av[4], bv[4];
#pragma unroll
            for (int n = 0; n < 4; ++n)
                bv[n] = *(const bf16x8*)(bBase + ((size_t)(t * 16 + n) << 9));
#pragma unroll
            for (int m = 0; m < 4; ++m) {
                int ra = m * 16 + cl;
                av[m] = *(const bf16x8*)&smH[ra * 256 + ((t * 32 + gg * 8) ^ ((ra & 7) << 3))];
            }
#pragma unroll
            for (int m = 0; m < 4; ++m)
#pragma unroll
                for (int n = 0; n < 4; ++n)
                    acc[m][n] = __builtin_amdgcn_mfma_f32_16x16x32_bf16(av[m], bv[n], acc[m][n], 0, 0, 0);
        }
    }

    // epilogue 2: hidden -> smH (in place; all GEMM2 reads of smH are done in-wave,
    // but other waves may still read -> barrier BEFORE overwrite)
    __syncthreads();
#pragma unroll
    for (int m = 0; m < 4; ++m)
#pragma unroll
        for (int n = 0; n < 4; ++n)
#pragma unroll
            for (int j = 0; j < 4; ++j) {
                int r = m * 16 + gg * 4 + j;
                int c = wid * 64 + n * 16 + cl;
                smH[r * 256 + (c ^ ((r & 7) << 3))] = f2bf(fast_tanh(acc[m][n][j] + b2v[n]));
            }
    __syncthreads();   // hidden2 visible

    // ---------------- heads + loss: wave wid owns rows [wid*16, +16) — NO barriers ----------------
    float lsum = 0.0f;
    {
        f32x4 acc_a = {0.f, 0.f, 0.f, 0.f}, acc_v = {0.f, 0.f, 0.f, 0.f};
        const unsigned short* wBase = Wavf + lane * 8;
#pragma unroll
        for (int kk = 0; kk < 8; ++kk) {
            int r = wid * 16 + cl;
            bf16x8 av = *(const bf16x8*)&smH[r * 256 + ((kk * 32 + gg * 8) ^ ((r & 7) << 3))];
            bf16x8 bva = *(const bf16x8*)(wBase + ((size_t)(kk * 2) << 9));
            bf16x8 bvv = *(const bf16x8*)(wBase + ((size_t)(kk * 2 + 1) << 9));
            acc_a = __builtin_amdgcn_mfma_f32_16x16x32_bf16(av, bva, acc_a, 0, 0, 0);
            acc_v = __builtin_amdgcn_mfma_f32_16x16x32_bf16(av, bvv, acc_v, 0, 0, 0);
        }

        const int t0 = bm0 + wid * 16;
#pragma unroll
        for (int j = 0; j < 4; ++j) {
            int t = t0 + gg * 4 + j;
            float lg = acc_a[j] + bav;
            float mx = lg;
#pragma unroll
            for (int dd = 1; dd < 16; dd <<= 1) mx = fmaxf(mx, __shfl_xor(mx, dd));
            float ex = __expf(lg - mx);
            float se = ex;
#pragma unroll
            for (int dd = 1; dd < 16; dd <<= 1) se += __shfl_xor(se, dd);
            float ls = __logf(se);
            float lp = lg - mx - ls;
            float pl = __expf(lp) * lp;
            float ent = pl;
#pragma unroll
            for (int dd = 1; dd < 16; dd <<= 1) ent += __shfl_xor(ent, dd);
            ent = -ent;
            int act = actions[t];
            float newlp = __shfl(lp, (lane & 48) | act);
            float val = __shfl(acc_v[j], lane & 48) + bc0;

            float lpo = logprobs[t];
            float at = (adv[t] - meanA) * rstdA;
            float rt = ret[t];
            float vo = values[t];
            float ratio = __expf(newlp - lpo);
            float rcl = fminf(fmaxf(ratio, 0.8f), 1.2f);
            float pg = fmaxf(-at * ratio, -at * rcl);
            float vcl = vo + fminf(fmaxf(val - vo, -0.2f), 0.2f);
            float dv = val - rt, dvc = vcl - rt;
            float vl = fmaxf(dv * dv, dvc * dvc);
            if (cl == 0) lsum += pg - 0.01f * ent + 0.25f * vl;
        }
        lsum += __shfl_xor(lsum, 16);
        lsum += __shfl_xor(lsum, 32);
    }
    __syncthreads();   // all smH reads done; reuse SM for final reduce
    float* red2 = (float*)SM;
    if (lane == 0) red2[wid] = lsum;
    __syncthreads();
    if (tid == 0) lossP[blockIdx.x] = red2[0] + red2[1] + red2[2] + red2[3];
}

__global__ void k_final(const float* __restrict__ lossP, float* __restrict__ out) {
    __shared__ float s[256];
    int i = threadIdx.x;
    s[i] = lossP[i] + lossP[i + 256] + lossP[i + 512] + lossP[i + 768];
    __syncthreads();
#pragma unroll
    for (int st = 128; st > 0; st >>= 1) {
        if (i < st) s[i] += s[i + st];
        __syncthreads();
    }
    if (i == 0) out[0] = s[0] * (1.0f / TT);
}

extern "C" void kernel_launch(void* const* d_in, const int* in_sizes, int n_in,
                              void* d_out, int out_size, void* d_ws, size_t ws_size,
                              hipStream_t stream) {
    const float* obs      = (const float*)d_in[0];
    const int*   actions  = (const int*)d_in[1];
    const float* logprobs = (const float*)d_in[2];
    const float* rewards  = (const float*)d_in[3];
    const float* terms    = (const float*)d_in[4];
    const float* values   = (const float*)d_in[5];
    const float* W1 = (const float*)d_in[6];
    const float* b1 = (const float*)d_in[7];
    const float* W2 = (const float*)d_in[8];
    const float* b2 = (const float*)d_in[9];
    const float* Wa = (const float*)d_in[10];
    const float* ba = (const float*)d_in[11];
    const float* Wc = (const float*)d_in[12];
    const float* bc = (const float*)d_in[13];

    char* ws = (char*)d_ws;
    unsigned short* W1Tf = (unsigned short*)(ws + 0);        // 262144 B
    unsigned short* W2Tf = (unsigned short*)(ws + 262144);   // 131072 B
    unsigned short* Wavf = (unsigned short*)(ws + 393216);   // 16384 B
    float* advp  = (float*)(ws + 409600);                    // 262144 B
    float* retp  = (float*)(ws + 671744);                    // 262144 B
    float* aggC  = (float*)(ws + 933888);                    // 1024 B
    float* aggD  = (float*)(ws + 934912);                    // 1024 B
    float* sumP  = (float*)(ws + 936960);                    // 2048 B
    float* stats = (float*)(ws + 939008);                    // 64 B
    float* lossP = (float*)(ws + 939072);                    // 4096 B

    k_prep_gae1<<<1056, 256, 0, stream>>>(W1, W2, Wa, Wc, W1Tf, W2Tf, Wavf,
                                          rewards, terms, values, aggC, aggD);
    k_gae3<<<256, 256, 0, stream>>>(rewards, terms, values, aggC, aggD, advp, retp, sumP);
    k_gae4<<<1, 256, 0, stream>>>(sumP, stats);
    k_mlp<<<1024, 256, 0, stream>>>(obs, actions, logprobs, values, b1, b2, ba, bc,
                                    W1Tf, W2Tf, Wavf, advp, retp, stats, lossP);
    k_final<<<1, 256, 0, stream>>>(lossP, (float*)d_out);
}